// Round 4
// baseline (3451.639 us; speedup 1.0000x reference)
//
#include <hip/hip_runtime.h>

typedef unsigned short u16;
typedef unsigned int u32;
typedef __attribute__((ext_vector_type(8))) short short8;
typedef __attribute__((ext_vector_type(4))) float f32x4;

#define B_ 64
#define D_ 1024
#define DM_ 1088
#define H_ 8
#define HD_ 136
#define DFF_ 2048
#define SN_ 512
#define DM3_ 3264

__device__ __forceinline__ u16 f2bf(float f) {
    union { float f; u32 u; } v; v.f = f;
    u32 r = v.u + 0x7FFFu + ((v.u >> 16) & 1u);
    return (u16)(r >> 16);
}
__device__ __forceinline__ float bf2f(u16 u) {
    union { u32 u; float f; } v; v.u = (u32)u << 16; return v.f;
}

__device__ __forceinline__ void gload16(const void* g, void* l) {
    __builtin_amdgcn_global_load_lds(
        (const __attribute__((address_space(1))) u32*)g,
        (__attribute__((address_space(3))) u32*)l, 16, 0, 0);
}

// ---------------- weight fp32 -> bf16 ----------------
__global__ void cvt_bf16(const float* __restrict__ in, u16* __restrict__ out, int n) {
    int i = blockIdx.x * 256 + threadIdx.x;
    if (i < n) out[i] = f2bf(in[i]);
}

// ---------------- build S (bf16) ----------------
__global__ void build_s(const float* __restrict__ qe, const float* __restrict__ sa,
                        const float* __restrict__ si, const float* __restrict__ ref,
                        u16* __restrict__ xb) {
    int idx = blockIdx.x * 256 + threadIdx.x;
    const int total = B_ * SN_ * (DM_ / 4);
    if (idx >= total) return;
    int b = idx / (SN_ * 272);
    int rem = idx - b * (SN_ * 272);
    int j = rem / 272;
    int c4 = rem - j * 272;
    int col = c4 * 4;
    float4 v;
    if (col < D_) {
        const float* src;
        if (j == 0)       src = qe + (size_t)b * D_;
        else if (j < 13)  src = sa + ((size_t)b * 12 + (j - 1)) * D_;
        else if (j < 25)  src = si + ((size_t)b * 12 + (j - 13)) * D_;
        else              src = ref + ((size_t)b * 487 + (j - 25)) * D_;
        v = *(const float4*)(src + col);
    } else {
        float f = (j >= 1 && j < 13) ? 1.f : ((j >= 13 && j < 25) ? -1.f : 0.f);
        v = make_float4(f, f, f, f);
    }
    size_t off = ((size_t)b * SN_ + j) * DM_ + col;
    ushort4 p; p.x = f2bf(v.x); p.y = f2bf(v.y); p.z = f2bf(v.z); p.w = f2bf(v.w);
    *(ushort4*)(xb + off) = p;
}

// ---------------- mask bias ----------------
__global__ void build_mask(const int* __restrict__ asz, const int* __restrict__ isz,
                           float* __restrict__ mb) {
    int idx = blockIdx.x * 256 + threadIdx.x;
    if (idx >= B_ * SN_) return;
    int b = idx >> 9, j = idx & 511;
    int ra = asz[b], ri = isz[b];
    bool m = (j == 0) || (j >= 1 && j < 13 && j < ra + 1)
          || (j >= 13 && j < 25 && j < ri + 13) || (j >= 25 && j < ri + 13);
    mb[idx] = m ? -1e9f : 0.f;
}

// ---------------- GEMM: C[m,n] = bf16(A[m,:]·Bt[n,:] + bias[n]) ----------------
// EPI: 0 = bf16 store, 1 = relu + bf16 store
template<int EPI>
__global__ __launch_bounds__(256)
void gemm_bt(const u16* __restrict__ A, int lda, const u16* __restrict__ Bt,
             const float* __restrict__ bias, u16* __restrict__ C,
             int N, int K) {
    __shared__ __align__(16) u16 As[128 * 64];
    __shared__ __align__(16) u16 Bs[128 * 64];
    const int tid = threadIdx.x;
    const int lane = tid & 63;
    const int l16 = lane & 15;
    const int lhi = lane >> 4;
    const int wave = tid >> 6;
    const int bm = blockIdx.y * 128;
    const int bn = blockIdx.x * 128;
    const int wr = (wave >> 1) * 64;
    const int wc = (wave & 1) * 64;
    f32x4 acc[4][4] = {};
    const int KT = K >> 6;
    for (int kt = 0; kt < KT; ++kt) {
        const int k0 = kt << 6;
        #pragma unroll
        for (int i = 0; i < 4; ++i) {
            int c = i * 256 + tid;
            int row = c >> 3;
            int col = (c & 7) << 3;
            gload16(A + (size_t)(bm + row) * lda + k0 + col, &As[c << 3]);
            int nr = bn + row; nr = nr < N ? nr : N - 1;
            gload16(Bt + (size_t)nr * K + k0 + col, &Bs[c << 3]);
        }
        __syncthreads();
        #pragma unroll
        for (int kk = 0; kk < 2; ++kk) {
            short8 af[4], bfr[4];
            #pragma unroll
            for (int m = 0; m < 4; ++m)
                af[m] = *(const short8*)&As[(wr + m * 16 + l16) * 64 + kk * 32 + lhi * 8];
            #pragma unroll
            for (int n = 0; n < 4; ++n)
                bfr[n] = *(const short8*)&Bs[(wc + n * 16 + l16) * 64 + kk * 32 + lhi * 8];
            #pragma unroll
            for (int m = 0; m < 4; ++m)
                #pragma unroll
                for (int n = 0; n < 4; ++n)
                    acc[m][n] = __builtin_amdgcn_mfma_f32_16x16x32_bf16(af[m], bfr[n], acc[m][n], 0, 0, 0);
        }
        __syncthreads();
    }
    #pragma unroll
    for (int n = 0; n < 4; ++n) {
        int col = bn + wc + n * 16 + l16;
        if (col >= N) continue;
        float bv = bias[col];
        #pragma unroll
        for (int m = 0; m < 4; ++m) {
            #pragma unroll
            for (int r = 0; r < 4; ++r) {
                int row = bm + wr + m * 16 + lhi * 4 + r;
                float v = acc[m][n][r] + bv;
                if (EPI == 1) v = v > 0.f ? v : 0.f;
                C[(size_t)row * N + col] = f2bf(v);
            }
        }
    }
}

// ---------------- attention ----------------
// grid: (8 qblocks, H, B), 256 threads (4 waves), each wave = 16 queries.
// Output O is written back into the Q slot of qkv (each block touches only
// the (rows, head) slice that it alone reads -> no cross-block hazard).
__global__ __launch_bounds__(256)
void attn_kernel(u16* __restrict__ qkv, const float* __restrict__ maskbias) {
    __shared__ __align__(16) u16 kls[64 * 168];   // K tile [64 keys][168 (136 + zero pad)]
    __shared__ __align__(16) u16 vts[144 * 72];   // V^T tile [144 d (136 + zero)][72 (64 keys + pad)]
    __shared__ __align__(16) u16 pls[4][16 * 72]; // per-wave P [16 q][72]
    const int qb = blockIdx.x, h = blockIdx.y, b = blockIdx.z;
    const int tid = threadIdx.x;
    const int lane = tid & 63;
    const int l16 = lane & 15;
    const int lhi = lane >> 4;
    const int wave = tid >> 6;

    // zero pads (K cols 136..167, V^T rows 136..143)
    for (int i = tid; i < 64 * 32; i += 256) { int r = i >> 5, c = 136 + (i & 31); kls[r * 168 + c] = 0; }
    for (int i = tid; i < 8 * 64;  i += 256) { int r = 136 + (i >> 6), c = i & 63; vts[r * 72 + c] = 0; }

    // Q fragments (head dim padded 136 -> 160)
    const int q0 = qb * 64 + wave * 16;
    const size_t qrow = ((size_t)b * SN_ + q0 + l16) * DM3_ + (size_t)h * HD_;
    short8 qf[5];
    #pragma unroll
    for (int ks = 0; ks < 5; ++ks) {
        int c0 = ks * 32 + lhi * 8;
        if (c0 < HD_) qf[ks] = *(const short8*)(qkv + qrow + c0);
        else { short8 z = {0,0,0,0,0,0,0,0}; qf[ks] = z; }
    }
    const float inv = 0.08574929257125442f; // 1/sqrt(136)
    f32x4 o[9] = {};
    float mrun[4], lrun[4];
    #pragma unroll
    for (int r = 0; r < 4; ++r) { mrun[r] = -1e30f; lrun[r] = 0.f; }

    for (int kt = 0; kt < 8; ++kt) {
        __syncthreads();
        // stage K tile
        const size_t kbase = ((size_t)b * SN_ + kt * 64) * DM3_ + DM_ + (size_t)h * HD_;
        const size_t vbase = kbase + DM_;
        for (int c = tid; c < 64 * 17; c += 256) {
            int r = c / 17, cc = c - r * 17;
            uint4 v = *(const uint4*)(qkv + kbase + (size_t)r * DM3_ + cc * 8);
            *(uint4*)&kls[r * 168 + cc * 8] = v;
        }
        // stage V tile transposed
        for (int c = tid; c < 64 * 17; c += 256) {
            int r = c / 17, cc = c - r * 17;
            uint4 v = *(const uint4*)(qkv + vbase + (size_t)r * DM3_ + cc * 8);
            const u16* pv = (const u16*)&v;
            #pragma unroll
            for (int t = 0; t < 8; ++t) vts[(cc * 8 + t) * 72 + r] = pv[t];
        }
        __syncthreads();

        // scores: 16 q x 64 k
        f32x4 s[4] = {};
        #pragma unroll
        for (int ks = 0; ks < 5; ++ks) {
            #pragma unroll
            for (int n = 0; n < 4; ++n) {
                short8 bfr = *(const short8*)&kls[(n * 16 + l16) * 168 + ks * 32 + lhi * 8];
                s[n] = __builtin_amdgcn_mfma_f32_16x16x32_bf16(qf[ks], bfr, s[n], 0, 0, 0);
            }
        }
        #pragma unroll
        for (int n = 0; n < 4; ++n) {
            float mb = maskbias[b * SN_ + kt * 64 + n * 16 + l16];
            #pragma unroll
            for (int r = 0; r < 4; ++r) s[n][r] = s[n][r] * inv + mb;
        }
        // online softmax (row = lhi*4 + r)
        float tmax[4];
        #pragma unroll
        for (int r = 0; r < 4; ++r)
            tmax[r] = fmaxf(fmaxf(s[0][r], s[1][r]), fmaxf(s[2][r], s[3][r]));
        #pragma unroll
        for (int msk = 1; msk <= 8; msk <<= 1)
            #pragma unroll
            for (int r = 0; r < 4; ++r) tmax[r] = fmaxf(tmax[r], __shfl_xor(tmax[r], msk));
        float scale[4];
        #pragma unroll
        for (int r = 0; r < 4; ++r) {
            float mn = fmaxf(mrun[r], tmax[r]);
            scale[r] = __expf(mrun[r] - mn);
            mrun[r] = mn;
        }
        float rs[4] = {0.f, 0.f, 0.f, 0.f};
        u16 pb[4][4];
        #pragma unroll
        for (int n = 0; n < 4; ++n)
            #pragma unroll
            for (int r = 0; r < 4; ++r) {
                float p = __expf(s[n][r] - mrun[r]);
                rs[r] += p;
                pb[n][r] = f2bf(p);
            }
        #pragma unroll
        for (int msk = 1; msk <= 8; msk <<= 1)
            #pragma unroll
            for (int r = 0; r < 4; ++r) rs[r] += __shfl_xor(rs[r], msk);
        #pragma unroll
        for (int r = 0; r < 4; ++r) lrun[r] = lrun[r] * scale[r] + rs[r];
        #pragma unroll
        for (int f = 0; f < 9; ++f)
            #pragma unroll
            for (int r = 0; r < 4; ++r) o[f][r] *= scale[r];
        // P -> LDS (per-wave)
        #pragma unroll
        for (int n = 0; n < 4; ++n)
            #pragma unroll
            for (int r = 0; r < 4; ++r)
                pls[wave][(lhi * 4 + r) * 72 + n * 16 + l16] = pb[n][r];
        // PV
        #pragma unroll
        for (int ks2 = 0; ks2 < 2; ++ks2) {
            short8 pa = *(const short8*)&pls[wave][l16 * 72 + ks2 * 32 + lhi * 8];
            #pragma unroll
            for (int f = 0; f < 9; ++f) {
                short8 bv = *(const short8*)&vts[(l16 + f * 16) * 72 + ks2 * 32 + lhi * 8];
                o[f] = __builtin_amdgcn_mfma_f32_16x16x32_bf16(pa, bv, o[f], 0, 0, 0);
            }
        }
    }
    // write O (bf16) into the Q slot
    #pragma unroll
    for (int f = 0; f < 9; ++f) {
        int d = f * 16 + l16;
        if (d < HD_) {
            #pragma unroll
            for (int r = 0; r < 4; ++r) {
                size_t row = (size_t)b * SN_ + q0 + lhi * 4 + r;
                qkv[row * DM3_ + h * HD_ + d] = f2bf(o[f][r] / lrun[r]);
            }
        }
    }
}

// ---------------- residual + LayerNorm (bf16 in/out, fp32 math) ----------------
__global__ __launch_bounds__(256)
void add_ln(u16* __restrict__ x, const u16* __restrict__ o,
            const float* __restrict__ w, const float* __restrict__ bb) {
    const int row = blockIdx.x;
    const int tid = threadIdx.x;
    u16* xr = x + (size_t)row * DM_;
    const u16* orr = o + (size_t)row * DM_;
    float v0[4], v1[4];
    float s = 0.f, s2 = 0.f;
    {
        ushort4 a = ((const ushort4*)xr)[tid];
        ushort4 c = ((const ushort4*)orr)[tid];
        v0[0] = bf2f(a.x) + bf2f(c.x); v0[1] = bf2f(a.y) + bf2f(c.y);
        v0[2] = bf2f(a.z) + bf2f(c.z); v0[3] = bf2f(a.w) + bf2f(c.w);
        #pragma unroll
        for (int t = 0; t < 4; ++t) { s += v0[t]; s2 += v0[t] * v0[t]; }
    }
    const bool has2 = tid < 16;
    if (has2) {
        ushort4 a = ((const ushort4*)xr)[256 + tid];
        ushort4 c = ((const ushort4*)orr)[256 + tid];
        v1[0] = bf2f(a.x) + bf2f(c.x); v1[1] = bf2f(a.y) + bf2f(c.y);
        v1[2] = bf2f(a.z) + bf2f(c.z); v1[3] = bf2f(a.w) + bf2f(c.w);
        #pragma unroll
        for (int t = 0; t < 4; ++t) { s += v1[t]; s2 += v1[t] * v1[t]; }
    }
    #pragma unroll
    for (int m = 32; m >= 1; m >>= 1) { s += __shfl_xor(s, m); s2 += __shfl_xor(s2, m); }
    __shared__ float red[8];
    const int wave = tid >> 6, lane = tid & 63;
    if (lane == 0) { red[wave] = s; red[4 + wave] = s2; }
    __syncthreads();
    s = red[0] + red[1] + red[2] + red[3];
    s2 = red[4] + red[5] + red[6] + red[7];
    const float mean = s * (1.f / DM_);
    float var = s2 * (1.f / DM_) - mean * mean;
    const float rstd = rsqrtf(fmaxf(var, 0.f) + 1e-5f);
    {
        float4 wv = ((const float4*)w)[tid], bv = ((const float4*)bb)[tid];
        ushort4 y;
        y.x = f2bf((v0[0] - mean) * rstd * wv.x + bv.x);
        y.y = f2bf((v0[1] - mean) * rstd * wv.y + bv.y);
        y.z = f2bf((v0[2] - mean) * rstd * wv.z + bv.z);
        y.w = f2bf((v0[3] - mean) * rstd * wv.w + bv.w);
        ((ushort4*)xr)[tid] = y;
    }
    if (has2) {
        float4 wv = ((const float4*)w)[256 + tid], bv = ((const float4*)bb)[256 + tid];
        ushort4 y;
        y.x = f2bf((v1[0] - mean) * rstd * wv.x + bv.x);
        y.y = f2bf((v1[1] - mean) * rstd * wv.y + bv.y);
        y.z = f2bf((v1[2] - mean) * rstd * wv.z + bv.z);
        y.w = f2bf((v1[3] - mean) * rstd * wv.w + bv.w);
        ((ushort4*)xr)[256 + tid] = y;
    }
}

// ---------------- extract outputs (bf16 x -> fp32 out) ----------------
__global__ void extract_out(const u16* __restrict__ x, float* __restrict__ out) {
    int idx = blockIdx.x * 256 + threadIdx.x;
    const int total = B_ * 25 * D_;
    if (idx >= total) return;
    int b = idx / (25 * D_);
    int rem = idx - b * 25 * D_;
    int s = rem / D_;
    int c = rem - s * D_;
    float v = bf2f(x[((size_t)b * SN_ + s) * DM_ + c]);
    size_t dst;
    if (s == 0)       dst = (size_t)b * D_ + c;
    else if (s < 13)  dst = (size_t)B_ * D_ + ((size_t)b * 12 + (s - 1)) * D_ + c;
    else              dst = (size_t)B_ * D_ * 13 + ((size_t)b * 12 + (s - 13)) * D_ + c;
    out[dst] = v;
}

extern "C" void kernel_launch(void* const* d_in, const int* in_sizes, int n_in,
                              void* d_out, int out_size, void* d_ws, size_t ws_size,
                              hipStream_t stream) {
    const float* q_emb = (const float*)d_in[0];
    const float* sa_emb = (const float*)d_in[1];
    const float* si_emb = (const float*)d_in[2];
    const int* asz = (const int*)d_in[3];
    const int* isz = (const int*)d_in[4];
    const float* refset = (const float*)d_in[5];
    const float* Wqkv = (const float*)d_in[6];
    const float* bqkv = (const float*)d_in[7];
    const float* Wo = (const float*)d_in[8];
    const float* bo = (const float*)d_in[9];
    const float* ln1w = (const float*)d_in[10];
    const float* ln1b = (const float*)d_in[11];
    const float* W1 = (const float*)d_in[12];
    const float* b1 = (const float*)d_in[13];
    const float* W2 = (const float*)d_in[14];
    const float* b2 = (const float*)d_in[15];
    const float* ln2w = (const float*)d_in[16];
    const float* ln2b = (const float*)d_in[17];

    char* ws = (char*)d_ws;
    auto alloc = [&](size_t bytes) { char* p = ws; ws += (bytes + 255) & ~(size_t)255; return p; };
    const size_t NW_QKV = (size_t)2 * DM3_ * DM_;
    const size_t NW_O = (size_t)2 * DM_ * DM_;
    const size_t NW_1 = (size_t)2 * DFF_ * DM_;
    const size_t NROW = (size_t)B_ * SN_;

    u16* wqkv_b = (u16*)alloc(NW_QKV * 2);   // 14.2 MB
    u16* wo_b   = (u16*)alloc(NW_O * 2);     //  4.7 MB
    u16* w1_b   = (u16*)alloc(NW_1 * 2);     //  8.9 MB
    u16* w2_b   = (u16*)alloc(NW_1 * 2);     //  8.9 MB
    float* mb   = (float*)alloc(NROW * 4);   //  0.13 MB
    u16* xb     = (u16*)alloc(NROW * DM_ * 2);   // 71.3 MB
    u16* qkvb   = (u16*)alloc(NROW * DM3_ * 2);  // 213.9 MB (aliased by FFN hidden)
    u16* ob     = (u16*)alloc(NROW * DM_ * 2);   // 71.3 MB
    u16* bh     = qkvb;  // FFN hidden aliases qkv region (dead after Wo GEMM)
    // total ~393 MB

    // weights -> bf16
    cvt_bf16<<<(int)((NW_QKV + 255) / 256), 256, 0, stream>>>(Wqkv, wqkv_b, (int)NW_QKV);
    cvt_bf16<<<(int)((NW_O + 255) / 256), 256, 0, stream>>>(Wo, wo_b, (int)NW_O);
    cvt_bf16<<<(int)((NW_1 + 255) / 256), 256, 0, stream>>>(W1, w1_b, (int)NW_1);
    cvt_bf16<<<(int)((NW_1 + 255) / 256), 256, 0, stream>>>(W2, w2_b, (int)NW_1);

    // S + mask
    {
        int total = B_ * SN_ * (DM_ / 4);
        build_s<<<(total + 255) / 256, 256, 0, stream>>>(q_emb, sa_emb, si_emb, refset, xb);
        build_mask<<<(B_ * SN_ + 255) / 256, 256, 0, stream>>>(asz, isz, mb);
    }

    const int MT = (int)(NROW / 128); // 256
    for (int l = 0; l < 2; ++l) {
        // QKV: [32768,1088] x [3264,1088]^T -> qkv bf16
        gemm_bt<0><<<dim3((DM3_ + 127) / 128, MT), 256, 0, stream>>>(
            xb, DM_, wqkv_b + (size_t)l * DM3_ * DM_, bqkv + (size_t)l * DM3_, qkvb, DM3_, DM_);
        // attention (O written into Q slot of qkvb)
        attn_kernel<<<dim3(8, H_, B_), 256, 0, stream>>>(qkvb, mb);
        // Wo: A = O (Q slot of qkvb, lda=3264) -> ob
        gemm_bt<0><<<dim3((DM_ + 127) / 128, MT), 256, 0, stream>>>(
            qkvb, DM3_, wo_b + (size_t)l * DM_ * DM_, bo + (size_t)l * DM_, ob, DM_, DM_);
        add_ln<<<(int)NROW, 256, 0, stream>>>(xb, ob, ln1w + (size_t)l * DM_, ln1b + (size_t)l * DM_);
        // FFN
        gemm_bt<1><<<dim3(DFF_ / 128, MT), 256, 0, stream>>>(
            xb, DM_, w1_b + (size_t)l * DFF_ * DM_, b1 + (size_t)l * DFF_, bh, DFF_, DM_);
        gemm_bt<0><<<dim3((DM_ + 127) / 128, MT), 256, 0, stream>>>(
            bh, DFF_, w2_b + (size_t)l * DM_ * DFF_, b2 + (size_t)l * DM_, ob, DM_, DFF_);
        add_ln<<<(int)NROW, 256, 0, stream>>>(xb, ob, ln2w + (size_t)l * DM_, ln2b + (size_t)l * DM_);
    }

    extract_out<<<(B_ * 25 * D_ + 255) / 256, 256, 0, stream>>>(xb, (float*)d_out);
}

// Round 5
// 3040.544 us; speedup vs baseline: 1.1352x; 1.1352x over previous
//
#include <hip/hip_runtime.h>

typedef unsigned short u16;
typedef unsigned int u32;
typedef __attribute__((ext_vector_type(8))) short short8;
typedef __attribute__((ext_vector_type(4))) float f32x4;

#define B_ 64
#define D_ 1024
#define DM_ 1088
#define H_ 8
#define HD_ 136
#define DFF_ 2048
#define SN_ 512
#define DM3_ 3264

__device__ __forceinline__ u16 f2bf(float f) {
    union { float f; u32 u; } v; v.f = f;
    u32 r = v.u + 0x7FFFu + ((v.u >> 16) & 1u);
    return (u16)(r >> 16);
}
__device__ __forceinline__ float bf2f(u16 u) {
    union { u32 u; float f; } v; v.u = (u32)u << 16; return v.f;
}

__device__ __forceinline__ void gload16(const void* g, void* l) {
    __builtin_amdgcn_global_load_lds(
        (const __attribute__((address_space(1))) u32*)g,
        (__attribute__((address_space(3))) u32*)l, 16, 0, 0);
}

// ---------------- weight fp32 -> bf16 ----------------
__global__ void cvt_bf16(const float* __restrict__ in, u16* __restrict__ out, int n) {
    int i = blockIdx.x * 256 + threadIdx.x;
    if (i < n) out[i] = f2bf(in[i]);
}

// ---------------- build S (bf16) ----------------
__global__ void build_s(const float* __restrict__ qe, const float* __restrict__ sa,
                        const float* __restrict__ si, const float* __restrict__ ref,
                        u16* __restrict__ xb) {
    int idx = blockIdx.x * 256 + threadIdx.x;
    const int total = B_ * SN_ * (DM_ / 4);
    if (idx >= total) return;
    int b = idx / (SN_ * 272);
    int rem = idx - b * (SN_ * 272);
    int j = rem / 272;
    int c4 = rem - j * 272;
    int col = c4 * 4;
    float4 v;
    if (col < D_) {
        const float* src;
        if (j == 0)       src = qe + (size_t)b * D_;
        else if (j < 13)  src = sa + ((size_t)b * 12 + (j - 1)) * D_;
        else if (j < 25)  src = si + ((size_t)b * 12 + (j - 13)) * D_;
        else              src = ref + ((size_t)b * 487 + (j - 25)) * D_;
        v = *(const float4*)(src + col);
    } else {
        float f = (j >= 1 && j < 13) ? 1.f : ((j >= 13 && j < 25) ? -1.f : 0.f);
        v = make_float4(f, f, f, f);
    }
    size_t off = ((size_t)b * SN_ + j) * DM_ + col;
    ushort4 p; p.x = f2bf(v.x); p.y = f2bf(v.y); p.z = f2bf(v.z); p.w = f2bf(v.w);
    *(ushort4*)(xb + off) = p;
}

// ---------------- mask bias ----------------
__global__ void build_mask(const int* __restrict__ asz, const int* __restrict__ isz,
                           float* __restrict__ mb) {
    int idx = blockIdx.x * 256 + threadIdx.x;
    if (idx >= B_ * SN_) return;
    int b = idx >> 9, j = idx & 511;
    int ra = asz[b], ri = isz[b];
    bool m = (j == 0) || (j >= 1 && j < 13 && j < ra + 1)
          || (j >= 13 && j < 25 && j < ri + 13) || (j >= 25 && j < ri + 13);
    mb[idx] = m ? -1e9f : 0.f;
}

// ---------------- GEMM 256x256, BK=32, 8 waves, 3-deep LDS pipeline ----------
// C[m,n] = bf16(A[m,:]·Bt[n,:] + bias[n]); EPI: 0 = store, 1 = relu+store.
// Pipeline: tile t+2 staged during tile t (buffers mod 3); raw s_barrier +
// counted vmcnt(4) per tile boundary (never 0 except tail). LDS reads are
// XOR-swizzled (slot ^= (row>>1)&3) with pre-swizzled global source.
template<int EPI>
__global__ __launch_bounds__(512, 2)
void gemm256(const u16* __restrict__ A, int lda, const u16* __restrict__ Bt,
             const float* __restrict__ bias, u16* __restrict__ C,
             int N, int K, int nbx) {
    __shared__ __align__(16) u16 As3[3][256 * 32];
    __shared__ __align__(16) u16 Bs3[3][256 * 32];
    const int tid = threadIdx.x;
    const int lane = tid & 63;
    const int l16 = lane & 15;
    const int lhi = lane >> 4;
    const int wave = tid >> 6;      // 0..7
    const int arow = (wave >> 2) * 128;  // wave row-half
    const int bcol = (wave & 3) * 64;    // wave col-quarter

    // XCD-aware swizzle (nwg = 128*nbx, always % 8 == 0)
    const int nwg = gridDim.x;
    const int cpx = nwg >> 3;
    const int bid = blockIdx.x;
    const int swz = (bid & 7) * cpx + (bid >> 3);
    const int by = swz / nbx;
    const int bx = swz - by * nbx;
    const int bm = by * 256;
    const int bn = bx * 256;

    auto STAGE = [&](int buf, int kt) {
        const int k0 = kt << 5;
        u16* as = As3[buf];
        u16* bs = Bs3[buf];
        #pragma unroll
        for (int p = 0; p < 2; ++p) {
            int c = p * 512 + tid;
            int row = c >> 2;
            int slot = (c & 3) ^ ((row >> 1) & 3);   // inverse-swizzled source
            gload16(A + (size_t)(bm + row) * lda + k0 + slot * 8, as + c * 8);
            int nr = bn + row; nr = nr < N ? nr : N - 1;
            gload16(Bt + (size_t)nr * K + k0 + slot * 8, bs + c * 8);
        }
    };

    f32x4 acc[8][4] = {};
    const int KT = K >> 5;

    // prologue: stage tiles 0,1; wait tile 0 (4 newest = tile 1 outstanding)
    STAGE(0, 0);
    STAGE(1, 1);
    asm volatile("s_waitcnt vmcnt(4)" ::: "memory");
    __builtin_amdgcn_sched_barrier(0);
    __builtin_amdgcn_s_barrier();
    asm volatile("" ::: "memory");

    int buf = 0, buf2 = 2;
    for (int t = 0; t < KT; ++t) {
        const bool more = (t + 2) < KT;
        if (more) STAGE(buf2, t + 2);
        const u16* as = As3[buf];
        const u16* bs = Bs3[buf];
        short8 bfr[4], af[8];
        #pragma unroll
        for (int n = 0; n < 4; ++n) {
            int row = bcol + n * 16 + l16;
            bfr[n] = *(const short8*)&bs[row * 32 + ((lhi ^ ((row >> 1) & 3)) << 3)];
        }
        #pragma unroll
        for (int m = 0; m < 8; ++m) {
            int row = arow + m * 16 + l16;
            af[m] = *(const short8*)&as[row * 32 + ((lhi ^ ((row >> 1) & 3)) << 3)];
        }
        __builtin_amdgcn_s_setprio(1);
        #pragma unroll
        for (int m = 0; m < 8; ++m)
            #pragma unroll
            for (int n = 0; n < 4; ++n)
                acc[m][n] = __builtin_amdgcn_mfma_f32_16x16x32_bf16(af[m], bfr[n], acc[m][n], 0, 0, 0);
        __builtin_amdgcn_s_setprio(0);
        if (t < KT - 1) {
            if (more) asm volatile("s_waitcnt vmcnt(4)" ::: "memory");
            else      asm volatile("s_waitcnt vmcnt(0)" ::: "memory");
            __builtin_amdgcn_sched_barrier(0);
            __builtin_amdgcn_s_barrier();
            asm volatile("" ::: "memory");
        }
        buf = buf == 2 ? 0 : buf + 1;
        buf2 = buf2 == 2 ? 0 : buf2 + 1;
    }

    #pragma unroll
    for (int n = 0; n < 4; ++n) {
        int col = bn + bcol + n * 16 + l16;
        if (col >= N) continue;
        float bv = bias[col];
        #pragma unroll
        for (int m = 0; m < 8; ++m) {
            #pragma unroll
            for (int r = 0; r < 4; ++r) {
                int row = bm + arow + m * 16 + lhi * 4 + r;
                float v = acc[m][n][r] + bv;
                if (EPI == 1) v = v > 0.f ? v : 0.f;
                C[(size_t)row * N + col] = f2bf(v);
            }
        }
    }
}

// ---------------- attention ----------------
// grid: (8 qblocks, H, B), 256 threads (4 waves), each wave = 16 queries.
// Output O is written back into the Q slot of qkv (each block touches only
// the (rows, head) slice that it alone reads -> no cross-block hazard).
__global__ __launch_bounds__(256)
void attn_kernel(u16* __restrict__ qkv, const float* __restrict__ maskbias) {
    __shared__ __align__(16) u16 kls[64 * 168];   // K tile [64 keys][168 (136 + zero pad)]
    __shared__ __align__(16) u16 vts[144 * 72];   // V^T tile [144 d (136 + zero)][72 (64 keys + pad)]
    __shared__ __align__(16) u16 pls[4][16 * 72]; // per-wave P [16 q][72]
    const int qb = blockIdx.x, h = blockIdx.y, b = blockIdx.z;
    const int tid = threadIdx.x;
    const int lane = tid & 63;
    const int l16 = lane & 15;
    const int lhi = lane >> 4;
    const int wave = tid >> 6;

    // zero pads (K cols 136..167, V^T rows 136..143)
    for (int i = tid; i < 64 * 32; i += 256) { int r = i >> 5, c = 136 + (i & 31); kls[r * 168 + c] = 0; }
    for (int i = tid; i < 8 * 64;  i += 256) { int r = 136 + (i >> 6), c = i & 63; vts[r * 72 + c] = 0; }

    // Q fragments (head dim padded 136 -> 160)
    const int q0 = qb * 64 + wave * 16;
    const size_t qrow = ((size_t)b * SN_ + q0 + l16) * DM3_ + (size_t)h * HD_;
    short8 qf[5];
    #pragma unroll
    for (int ks = 0; ks < 5; ++ks) {
        int c0 = ks * 32 + lhi * 8;
        if (c0 < HD_) qf[ks] = *(const short8*)(qkv + qrow + c0);
        else { short8 z = {0,0,0,0,0,0,0,0}; qf[ks] = z; }
    }
    const float inv = 0.08574929257125442f; // 1/sqrt(136)
    f32x4 o[9] = {};
    float mrun[4], lrun[4];
    #pragma unroll
    for (int r = 0; r < 4; ++r) { mrun[r] = -1e30f; lrun[r] = 0.f; }

    for (int kt = 0; kt < 8; ++kt) {
        __syncthreads();
        // stage K tile (vectorized writes, lane-consecutive within rows)
        const size_t kbase = ((size_t)b * SN_ + kt * 64) * DM3_ + DM_ + (size_t)h * HD_;
        const size_t vbase = kbase + DM_;
        for (int c = tid; c < 64 * 17; c += 256) {
            int r = c / 17, cc = c - r * 17;
            uint4 v = *(const uint4*)(qkv + kbase + (size_t)r * DM3_ + cc * 8);
            *(uint4*)&kls[r * 168 + cc * 8] = v;
        }
        // stage V tile transposed. Lane <-> key mapping so the 8 scattered u16
        // LDS writes per thread are lane-consecutive (conflict-free); the old
        // lane<->dchunk mapping made all lanes of a wave hit one bank (stride
        // 8*72 u16 = 288 dwords = 0 mod 32).
        for (int c = tid; c < 64 * 17; c += 256) {
            int r = c & 63, cc = c >> 6;
            uint4 v = *(const uint4*)(qkv + vbase + (size_t)r * DM3_ + cc * 8);
            const u16* pv = (const u16*)&v;
            #pragma unroll
            for (int t = 0; t < 8; ++t) vts[(cc * 8 + t) * 72 + r] = pv[t];
        }
        __syncthreads();

        // scores: 16 q x 64 k
        f32x4 s[4] = {};
        #pragma unroll
        for (int ks = 0; ks < 5; ++ks) {
            #pragma unroll
            for (int n = 0; n < 4; ++n) {
                short8 bfr = *(const short8*)&kls[(n * 16 + l16) * 168 + ks * 32 + lhi * 8];
                s[n] = __builtin_amdgcn_mfma_f32_16x16x32_bf16(qf[ks], bfr, s[n], 0, 0, 0);
            }
        }
        #pragma unroll
        for (int n = 0; n < 4; ++n) {
            float mb = maskbias[b * SN_ + kt * 64 + n * 16 + l16];
            #pragma unroll
            for (int r = 0; r < 4; ++r) s[n][r] = s[n][r] * inv + mb;
        }
        // online softmax (row = lhi*4 + r)
        float tmax[4];
        #pragma unroll
        for (int r = 0; r < 4; ++r)
            tmax[r] = fmaxf(fmaxf(s[0][r], s[1][r]), fmaxf(s[2][r], s[3][r]));
        #pragma unroll
        for (int msk = 1; msk <= 8; msk <<= 1)
            #pragma unroll
            for (int r = 0; r < 4; ++r) tmax[r] = fmaxf(tmax[r], __shfl_xor(tmax[r], msk));
        float scale[4];
        #pragma unroll
        for (int r = 0; r < 4; ++r) {
            float mn = fmaxf(mrun[r], tmax[r]);
            scale[r] = __expf(mrun[r] - mn);
            mrun[r] = mn;
        }
        float rs[4] = {0.f, 0.f, 0.f, 0.f};
        u16 pb[4][4];
        #pragma unroll
        for (int n = 0; n < 4; ++n)
            #pragma unroll
            for (int r = 0; r < 4; ++r) {
                float p = __expf(s[n][r] - mrun[r]);
                rs[r] += p;
                pb[n][r] = f2bf(p);
            }
        #pragma unroll
        for (int msk = 1; msk <= 8; msk <<= 1)
            #pragma unroll
            for (int r = 0; r < 4; ++r) rs[r] += __shfl_xor(rs[r], msk);
        #pragma unroll
        for (int r = 0; r < 4; ++r) lrun[r] = lrun[r] * scale[r] + rs[r];
        #pragma unroll
        for (int f = 0; f < 9; ++f)
            #pragma unroll
            for (int r = 0; r < 4; ++r) o[f][r] *= scale[r];
        // P -> LDS (per-wave)
        #pragma unroll
        for (int n = 0; n < 4; ++n)
            #pragma unroll
            for (int r = 0; r < 4; ++r)
                pls[wave][(lhi * 4 + r) * 72 + n * 16 + l16] = pb[n][r];
        // PV
        #pragma unroll
        for (int ks2 = 0; ks2 < 2; ++ks2) {
            short8 pa = *(const short8*)&pls[wave][l16 * 72 + ks2 * 32 + lhi * 8];
            #pragma unroll
            for (int f = 0; f < 9; ++f) {
                short8 bv = *(const short8*)&vts[(l16 + f * 16) * 72 + ks2 * 32 + lhi * 8];
                o[f] = __builtin_amdgcn_mfma_f32_16x16x32_bf16(pa, bv, o[f], 0, 0, 0);
            }
        }
    }
    // write O (bf16) into the Q slot
    #pragma unroll
    for (int f = 0; f < 9; ++f) {
        int d = f * 16 + l16;
        if (d < HD_) {
            #pragma unroll
            for (int r = 0; r < 4; ++r) {
                size_t row = (size_t)b * SN_ + q0 + lhi * 4 + r;
                qkv[row * DM3_ + h * HD_ + d] = f2bf(o[f][r] / lrun[r]);
            }
        }
    }
}

// ---------------- residual + LayerNorm (bf16 in/out, fp32 math) ----------------
__global__ __launch_bounds__(256)
void add_ln(u16* __restrict__ x, const u16* __restrict__ o,
            const float* __restrict__ w, const float* __restrict__ bb) {
    const int row = blockIdx.x;
    const int tid = threadIdx.x;
    u16* xr = x + (size_t)row * DM_;
    const u16* orr = o + (size_t)row * DM_;
    float v0[4], v1[4];
    float s = 0.f, s2 = 0.f;
    {
        ushort4 a = ((const ushort4*)xr)[tid];
        ushort4 c = ((const ushort4*)orr)[tid];
        v0[0] = bf2f(a.x) + bf2f(c.x); v0[1] = bf2f(a.y) + bf2f(c.y);
        v0[2] = bf2f(a.z) + bf2f(c.z); v0[3] = bf2f(a.w) + bf2f(c.w);
        #pragma unroll
        for (int t = 0; t < 4; ++t) { s += v0[t]; s2 += v0[t] * v0[t]; }
    }
    const bool has2 = tid < 16;
    if (has2) {
        ushort4 a = ((const ushort4*)xr)[256 + tid];
        ushort4 c = ((const ushort4*)orr)[256 + tid];
        v1[0] = bf2f(a.x) + bf2f(c.x); v1[1] = bf2f(a.y) + bf2f(c.y);
        v1[2] = bf2f(a.z) + bf2f(c.z); v1[3] = bf2f(a.w) + bf2f(c.w);
        #pragma unroll
        for (int t = 0; t < 4; ++t) { s += v1[t]; s2 += v1[t] * v1[t]; }
    }
    #pragma unroll
    for (int m = 32; m >= 1; m >>= 1) { s += __shfl_xor(s, m); s2 += __shfl_xor(s2, m); }
    __shared__ float red[8];
    const int wave = tid >> 6, lane = tid & 63;
    if (lane == 0) { red[wave] = s; red[4 + wave] = s2; }
    __syncthreads();
    s = red[0] + red[1] + red[2] + red[3];
    s2 = red[4] + red[5] + red[6] + red[7];
    const float mean = s * (1.f / DM_);
    float var = s2 * (1.f / DM_) - mean * mean;
    const float rstd = rsqrtf(fmaxf(var, 0.f) + 1e-5f);
    {
        float4 wv = ((const float4*)w)[tid], bv = ((const float4*)bb)[tid];
        ushort4 y;
        y.x = f2bf((v0[0] - mean) * rstd * wv.x + bv.x);
        y.y = f2bf((v0[1] - mean) * rstd * wv.y + bv.y);
        y.z = f2bf((v0[2] - mean) * rstd * wv.z + bv.z);
        y.w = f2bf((v0[3] - mean) * rstd * wv.w + bv.w);
        ((ushort4*)xr)[tid] = y;
    }
    if (has2) {
        float4 wv = ((const float4*)w)[256 + tid], bv = ((const float4*)bb)[256 + tid];
        ushort4 y;
        y.x = f2bf((v1[0] - mean) * rstd * wv.x + bv.x);
        y.y = f2bf((v1[1] - mean) * rstd * wv.y + bv.y);
        y.z = f2bf((v1[2] - mean) * rstd * wv.z + bv.z);
        y.w = f2bf((v1[3] - mean) * rstd * wv.w + bv.w);
        ((ushort4*)xr)[256 + tid] = y;
    }
}

// ---------------- extract outputs (bf16 x -> fp32 out) ----------------
__global__ void extract_out(const u16* __restrict__ x, float* __restrict__ out) {
    int idx = blockIdx.x * 256 + threadIdx.x;
    const int total = B_ * 25 * D_;
    if (idx >= total) return;
    int b = idx / (25 * D_);
    int rem = idx - b * 25 * D_;
    int s = rem / D_;
    int c = rem - s * D_;
    float v = bf2f(x[((size_t)b * SN_ + s) * DM_ + c]);
    size_t dst;
    if (s == 0)       dst = (size_t)b * D_ + c;
    else if (s < 13)  dst = (size_t)B_ * D_ + ((size_t)b * 12 + (s - 1)) * D_ + c;
    else              dst = (size_t)B_ * D_ * 13 + ((size_t)b * 12 + (s - 13)) * D_ + c;
    out[dst] = v;
}

extern "C" void kernel_launch(void* const* d_in, const int* in_sizes, int n_in,
                              void* d_out, int out_size, void* d_ws, size_t ws_size,
                              hipStream_t stream) {
    const float* q_emb = (const float*)d_in[0];
    const float* sa_emb = (const float*)d_in[1];
    const float* si_emb = (const float*)d_in[2];
    const int* asz = (const int*)d_in[3];
    const int* isz = (const int*)d_in[4];
    const float* refset = (const float*)d_in[5];
    const float* Wqkv = (const float*)d_in[6];
    const float* bqkv = (const float*)d_in[7];
    const float* Wo = (const float*)d_in[8];
    const float* bo = (const float*)d_in[9];
    const float* ln1w = (const float*)d_in[10];
    const float* ln1b = (const float*)d_in[11];
    const float* W1 = (const float*)d_in[12];
    const float* b1 = (const float*)d_in[13];
    const float* W2 = (const float*)d_in[14];
    const float* b2 = (const float*)d_in[15];
    const float* ln2w = (const float*)d_in[16];
    const float* ln2b = (const float*)d_in[17];

    char* ws = (char*)d_ws;
    auto alloc = [&](size_t bytes) { char* p = ws; ws += (bytes + 255) & ~(size_t)255; return p; };
    const size_t NW_QKV = (size_t)2 * DM3_ * DM_;
    const size_t NW_O = (size_t)2 * DM_ * DM_;
    const size_t NW_1 = (size_t)2 * DFF_ * DM_;
    const size_t NROW = (size_t)B_ * SN_;

    u16* wqkv_b = (u16*)alloc(NW_QKV * 2);   // 14.2 MB
    u16* wo_b   = (u16*)alloc(NW_O * 2);     //  4.7 MB
    u16* w1_b   = (u16*)alloc(NW_1 * 2);     //  8.9 MB
    u16* w2_b   = (u16*)alloc(NW_1 * 2);     //  8.9 MB
    float* mb   = (float*)alloc(NROW * 4);   //  0.13 MB
    u16* xb     = (u16*)alloc(NROW * DM_ * 2);   // 71.3 MB
    u16* qkvb   = (u16*)alloc(NROW * DM3_ * 2);  // 213.9 MB (aliased by FFN hidden)
    u16* ob     = (u16*)alloc(NROW * DM_ * 2);   // 71.3 MB
    u16* bh     = qkvb;  // FFN hidden aliases qkv region (dead after Wo GEMM)
    // total ~393 MB

    // weights -> bf16
    cvt_bf16<<<(int)((NW_QKV + 255) / 256), 256, 0, stream>>>(Wqkv, wqkv_b, (int)NW_QKV);
    cvt_bf16<<<(int)((NW_O + 255) / 256), 256, 0, stream>>>(Wo, wo_b, (int)NW_O);
    cvt_bf16<<<(int)((NW_1 + 255) / 256), 256, 0, stream>>>(W1, w1_b, (int)NW_1);
    cvt_bf16<<<(int)((NW_1 + 255) / 256), 256, 0, stream>>>(W2, w2_b, (int)NW_1);

    // S + mask
    {
        int total = B_ * SN_ * (DM_ / 4);
        build_s<<<(total + 255) / 256, 256, 0, stream>>>(q_emb, sa_emb, si_emb, refset, xb);
        build_mask<<<(B_ * SN_ + 255) / 256, 256, 0, stream>>>(asz, isz, mb);
    }

    const int MB256 = (int)(NROW / 256);  // 128 row-blocks
    const int NBX_QKV = (DM3_ + 255) / 256;  // 13
    const int NBX_DM  = (DM_ + 255) / 256;   // 5
    const int NBX_FF  = DFF_ / 256;          // 8
    for (int l = 0; l < 2; ++l) {
        // QKV: [32768,1088] x [3264,1088]^T -> qkv bf16
        gemm256<0><<<dim3(MB256 * NBX_QKV), 512, 0, stream>>>(
            xb, DM_, wqkv_b + (size_t)l * DM3_ * DM_, bqkv + (size_t)l * DM3_, qkvb, DM3_, DM_, NBX_QKV);
        // attention (O written into Q slot of qkvb)
        attn_kernel<<<dim3(8, H_, B_), 256, 0, stream>>>(qkvb, mb);
        // Wo: A = O (Q slot of qkvb, lda=3264) -> ob
        gemm256<0><<<dim3(MB256 * NBX_DM), 512, 0, stream>>>(
            qkvb, DM3_, wo_b + (size_t)l * DM_ * DM_, bo + (size_t)l * DM_, ob, DM_, DM_, NBX_DM);
        add_ln<<<(int)NROW, 256, 0, stream>>>(xb, ob, ln1w + (size_t)l * DM_, ln1b + (size_t)l * DM_);
        // FFN
        gemm256<1><<<dim3(MB256 * NBX_FF), 512, 0, stream>>>(
            xb, DM_, w1_b + (size_t)l * DFF_ * DM_, b1 + (size_t)l * DFF_, bh, DFF_, DM_, NBX_FF);
        gemm256<0><<<dim3(MB256 * NBX_DM), 512, 0, stream>>>(
            bh, DFF_, w2_b + (size_t)l * DM_ * DFF_, b2 + (size_t)l * DM_, ob, DM_, DFF_, NBX_DM);
        add_ln<<<(int)NROW, 256, 0, stream>>>(xb, ob, ln2w + (size_t)l * DM_, ln2b + (size_t)l * DM_);
    }

    extract_out<<<(B_ * 25 * D_ + 255) / 256, 256, 0, stream>>>(xb, (float*)d_out);
}

// Round 6
// 2753.386 us; speedup vs baseline: 1.2536x; 1.1043x over previous
//
#include <hip/hip_runtime.h>

typedef unsigned short u16;
typedef unsigned int u32;
typedef __attribute__((ext_vector_type(8))) short short8;
typedef __attribute__((ext_vector_type(4))) float f32x4;

#define B_ 64
#define D_ 1024
#define DM_ 1088
#define H_ 8
#define HD_ 136
#define DFF_ 2048
#define SN_ 512
#define DM3_ 3264

__device__ __forceinline__ u16 f2bf(float f) {
    union { float f; u32 u; } v; v.f = f;
    u32 r = v.u + 0x7FFFu + ((v.u >> 16) & 1u);
    return (u16)(r >> 16);
}
__device__ __forceinline__ float bf2f(u16 u) {
    union { u32 u; float f; } v; v.u = (u32)u << 16; return v.f;
}

__device__ __forceinline__ void gload16(const void* g, void* l) {
    __builtin_amdgcn_global_load_lds(
        (const __attribute__((address_space(1))) u32*)g,
        (__attribute__((address_space(3))) u32*)l, 16, 0, 0);
}

// ---------------- weight fp32 -> bf16 ----------------
__global__ void cvt_bf16(const float* __restrict__ in, u16* __restrict__ out, int n) {
    int i = blockIdx.x * 256 + threadIdx.x;
    if (i < n) out[i] = f2bf(in[i]);
}

// ---------------- build S (bf16) ----------------
__global__ void build_s(const float* __restrict__ qe, const float* __restrict__ sa,
                        const float* __restrict__ si, const float* __restrict__ ref,
                        u16* __restrict__ xb) {
    int idx = blockIdx.x * 256 + threadIdx.x;
    const int total = B_ * SN_ * (DM_ / 4);
    if (idx >= total) return;
    int b = idx / (SN_ * 272);
    int rem = idx - b * (SN_ * 272);
    int j = rem / 272;
    int c4 = rem - j * 272;
    int col = c4 * 4;
    float4 v;
    if (col < D_) {
        const float* src;
        if (j == 0)       src = qe + (size_t)b * D_;
        else if (j < 13)  src = sa + ((size_t)b * 12 + (j - 1)) * D_;
        else if (j < 25)  src = si + ((size_t)b * 12 + (j - 13)) * D_;
        else              src = ref + ((size_t)b * 487 + (j - 25)) * D_;
        v = *(const float4*)(src + col);
    } else {
        float f = (j >= 1 && j < 13) ? 1.f : ((j >= 13 && j < 25) ? -1.f : 0.f);
        v = make_float4(f, f, f, f);
    }
    size_t off = ((size_t)b * SN_ + j) * DM_ + col;
    ushort4 p; p.x = f2bf(v.x); p.y = f2bf(v.y); p.z = f2bf(v.z); p.w = f2bf(v.w);
    *(ushort4*)(xb + off) = p;
}

// ---------------- mask bias ----------------
__global__ void build_mask(const int* __restrict__ asz, const int* __restrict__ isz,
                           float* __restrict__ mb) {
    int idx = blockIdx.x * 256 + threadIdx.x;
    if (idx >= B_ * SN_) return;
    int b = idx >> 9, j = idx & 511;
    int ra = asz[b], ri = isz[b];
    bool m = (j == 0) || (j >= 1 && j < 13 && j < ra + 1)
          || (j >= 13 && j < 25 && j < ri + 13) || (j >= 25 && j < ri + 13);
    mb[idx] = m ? -1e9f : 0.f;
}

// ---------------- GEMM 256x256, BK=32, 8 waves, 3-deep pipeline, 2-phase ----
// C[m,n] = bf16(A[m,:]·Bt[n,:] + bias[n]); EPI: 0 = store, 1 = relu+store.
// Per K-step: 2 phases {ds_read frags | issue 2 gload_lds of tile t+2 |
// barrier | lgkm0 | 16 MFMA | barrier}; one counted vmcnt(4) per step.
// LDS reads XOR-swizzled (slot ^= (row>>1)&3), pre-swizzled global source.
// Epilogue: stage C through LDS, store 512B contiguous row segments.
template<int EPI>
__global__ __launch_bounds__(512, 2)
void gemm256(const u16* __restrict__ A, int lda, const u16* __restrict__ Bt,
             const float* __restrict__ bias, u16* __restrict__ C,
             int N, int K, int nbx) {
    __shared__ __align__(16) u16 As3[3][256 * 32];
    __shared__ __align__(16) u16 Bs3[3][256 * 32];
    const int tid = threadIdx.x;
    const int lane = tid & 63;
    const int l16 = lane & 15;
    const int lhi = lane >> 4;
    const int wave = tid >> 6;      // 0..7
    const int arow = (wave >> 2) * 128;  // wave row-half
    const int bcol = (wave & 3) * 64;    // wave col-quarter

    // XCD-aware swizzle (nwg = 128*nbx, always % 8 == 0)
    const int nwg = gridDim.x;
    const int cpx = nwg >> 3;
    const int bid = blockIdx.x;
    const int swz = (bid & 7) * cpx + (bid >> 3);
    const int by = swz / nbx;
    const int bx = swz - by * nbx;
    const int bm = by * 256;
    const int bn = bx * 256;

    auto STAGE = [&](int buf, int kt) {
        const int k0 = kt << 5;
        u16* as = As3[buf];
        u16* bs = Bs3[buf];
        #pragma unroll
        for (int p = 0; p < 2; ++p) {
            int c = p * 512 + tid;
            int row = c >> 2;
            int slot = (c & 3) ^ ((row >> 1) & 3);   // inverse-swizzled source
            gload16(A + (size_t)(bm + row) * lda + k0 + slot * 8, as + c * 8);
            int nr = bn + row; nr = nr < N ? nr : N - 1;
            gload16(Bt + (size_t)nr * K + k0 + slot * 8, bs + c * 8);
        }
    };

    f32x4 acc[8][4] = {};
    const int KT = K >> 5;

    // prologue: stage tiles 0,1; wait tile 0 (tile 1's 4 ops stay in flight)
    STAGE(0, 0);
    STAGE(1, 1);
    asm volatile("s_waitcnt vmcnt(4)" ::: "memory");
    __builtin_amdgcn_sched_barrier(0);
    __builtin_amdgcn_s_barrier();

    int buf = 0, buf2 = 2;
    for (int t = 0; t < KT; ++t) {
        const bool more = (t + 2) < KT;
        const u16* as = As3[buf];
        const u16* bs = Bs3[buf];
        const int k0n = (t + 2) << 5;
        short8 af[4], bfr[4];
        // ---- phase 0: B frags + A rows [arow, arow+64); stage A-half t+2 ----
        #pragma unroll
        for (int n = 0; n < 4; ++n) {
            int row = bcol + n * 16 + l16;
            bfr[n] = *(const short8*)&bs[row * 32 + ((lhi ^ ((row >> 1) & 3)) << 3)];
        }
        #pragma unroll
        for (int m = 0; m < 4; ++m) {
            int row = arow + m * 16 + l16;
            af[m] = *(const short8*)&as[row * 32 + ((lhi ^ ((row >> 1) & 3)) << 3)];
        }
        if (more) {
            u16* dst = As3[buf2];
            #pragma unroll
            for (int p = 0; p < 2; ++p) {
                int c = p * 512 + tid;
                int row = c >> 2;
                int slot = (c & 3) ^ ((row >> 1) & 3);
                gload16(A + (size_t)(bm + row) * lda + k0n + slot * 8, dst + c * 8);
            }
        }
        __builtin_amdgcn_s_barrier();
        asm volatile("s_waitcnt lgkmcnt(0)" ::: "memory");
        __builtin_amdgcn_sched_barrier(0);
        __builtin_amdgcn_s_setprio(1);
        #pragma unroll
        for (int m = 0; m < 4; ++m)
            #pragma unroll
            for (int n = 0; n < 4; ++n)
                acc[m][n] = __builtin_amdgcn_mfma_f32_16x16x32_bf16(af[m], bfr[n], acc[m][n], 0, 0, 0);
        __builtin_amdgcn_s_setprio(0);
        __builtin_amdgcn_s_barrier();
        // ---- phase 1: A rows [arow+64, arow+128); stage B-half t+2 ----
        #pragma unroll
        for (int m = 0; m < 4; ++m) {
            int row = arow + 64 + m * 16 + l16;
            af[m] = *(const short8*)&as[row * 32 + ((lhi ^ ((row >> 1) & 3)) << 3)];
        }
        if (more) {
            u16* dst = Bs3[buf2];
            #pragma unroll
            for (int p = 0; p < 2; ++p) {
                int c = p * 512 + tid;
                int row = c >> 2;
                int slot = (c & 3) ^ ((row >> 1) & 3);
                int nr = bn + row; nr = nr < N ? nr : N - 1;
                gload16(Bt + (size_t)nr * K + k0n + slot * 8, dst + c * 8);
            }
        }
        __builtin_amdgcn_s_barrier();
        asm volatile("s_waitcnt lgkmcnt(0)" ::: "memory");
        __builtin_amdgcn_sched_barrier(0);
        __builtin_amdgcn_s_setprio(1);
        #pragma unroll
        for (int m = 0; m < 4; ++m)
            #pragma unroll
            for (int n = 0; n < 4; ++n)
                acc[4 + m][n] = __builtin_amdgcn_mfma_f32_16x16x32_bf16(af[m], bfr[n], acc[4 + m][n], 0, 0, 0);
        __builtin_amdgcn_s_setprio(0);
        if (t < KT - 1) {
            // gate tile t+1 complete; keep tile t+2's 4 loads in flight
            if (more) asm volatile("s_waitcnt vmcnt(4)" ::: "memory");
            else      asm volatile("s_waitcnt vmcnt(0)" ::: "memory");
            __builtin_amdgcn_sched_barrier(0);
            __builtin_amdgcn_s_barrier();
        }
        buf = buf == 2 ? 0 : buf + 1;
        buf2 = buf2 == 2 ? 0 : buf2 + 1;
    }

    // ---- epilogue: coalesced C-write via LDS (64-row quarters) ----
    __syncthreads();
    u16* cst = (u16*)As3;   // 48 KB >= 32 KB needed
    const int halfsel = wave >> 2;
    #pragma unroll
    for (int qr = 0; qr < 4; ++qr) {
        if ((qr >> 1) == halfsel) {
            const int mbase = (qr & 1) * 4;
            #pragma unroll
            for (int n = 0; n < 4; ++n) {
                int col = bcol + n * 16 + l16;
                int gc = bn + col;
                float bv = gc < N ? bias[gc] : 0.f;
                #pragma unroll
                for (int mm = 0; mm < 4; ++mm) {
                    int rq = mm * 16 + lhi * 4;
                    #pragma unroll
                    for (int r = 0; r < 4; ++r) {
                        float v = acc[mbase + mm][n][r] + bv;
                        if (EPI == 1) v = v > 0.f ? v : 0.f;
                        cst[(rq + r) * 256 + col] = f2bf(v);
                    }
                }
            }
        }
        __syncthreads();
        #pragma unroll
        for (int i = 0; i < 4; ++i) {
            int slot = i * 512 + tid;
            int row = slot >> 5;
            int chunk = slot & 31;
            int gc = bn + chunk * 8;
            if (gc < N) {
                uint4 v = *(const uint4*)&cst[row * 256 + chunk * 8];
                *(uint4*)&C[(size_t)(bm + qr * 64 + row) * N + gc] = v;
            }
        }
        __syncthreads();
    }
}

// ---------------- attention ----------------
// grid: (8 qblocks, H, B), 256 threads (4 waves), each wave = 16 queries.
// Output O is written back into the Q slot of qkv (each block touches only
// the (rows, head) slice that it alone reads -> no cross-block hazard).
__global__ __launch_bounds__(256)
void attn_kernel(u16* __restrict__ qkv, const float* __restrict__ maskbias) {
    __shared__ __align__(16) u16 kls[64 * 168];   // K tile [64 keys][168 (136 + zero pad)]
    __shared__ __align__(16) u16 vts[144 * 72];   // V^T tile [144 d (136 + zero)][72 (64 keys + pad)]
    __shared__ __align__(16) u16 pls[4][16 * 72]; // per-wave P [16 q][72]
    const int qb = blockIdx.x, h = blockIdx.y, b = blockIdx.z;
    const int tid = threadIdx.x;
    const int lane = tid & 63;
    const int l16 = lane & 15;
    const int lhi = lane >> 4;
    const int wave = tid >> 6;

    // zero pads (K cols 136..167, V^T rows 136..143)
    for (int i = tid; i < 64 * 32; i += 256) { int r = i >> 5, c = 136 + (i & 31); kls[r * 168 + c] = 0; }
    for (int i = tid; i < 8 * 64;  i += 256) { int r = 136 + (i >> 6), c = i & 63; vts[r * 72 + c] = 0; }

    // Q fragments (head dim padded 136 -> 160)
    const int q0 = qb * 64 + wave * 16;
    const size_t qrow = ((size_t)b * SN_ + q0 + l16) * DM3_ + (size_t)h * HD_;
    short8 qf[5];
    #pragma unroll
    for (int ks = 0; ks < 5; ++ks) {
        int c0 = ks * 32 + lhi * 8;
        if (c0 < HD_) qf[ks] = *(const short8*)(qkv + qrow + c0);
        else { short8 z = {0,0,0,0,0,0,0,0}; qf[ks] = z; }
    }
    const float inv = 0.08574929257125442f; // 1/sqrt(136)
    f32x4 o[9] = {};
    float mrun[4], lrun[4];
    #pragma unroll
    for (int r = 0; r < 4; ++r) { mrun[r] = -1e30f; lrun[r] = 0.f; }

    for (int kt = 0; kt < 8; ++kt) {
        __syncthreads();
        // stage K tile (vectorized writes, lane-consecutive within rows)
        const size_t kbase = ((size_t)b * SN_ + kt * 64) * DM3_ + DM_ + (size_t)h * HD_;
        const size_t vbase = kbase + DM_;
        for (int c = tid; c < 64 * 17; c += 256) {
            int r = c / 17, cc = c - r * 17;
            uint4 v = *(const uint4*)(qkv + kbase + (size_t)r * DM3_ + cc * 8);
            *(uint4*)&kls[r * 168 + cc * 8] = v;
        }
        // stage V tile transposed (lane <-> key mapping: conflict-free writes)
        for (int c = tid; c < 64 * 17; c += 256) {
            int r = c & 63, cc = c >> 6;
            uint4 v = *(const uint4*)(qkv + vbase + (size_t)r * DM3_ + cc * 8);
            const u16* pv = (const u16*)&v;
            #pragma unroll
            for (int t = 0; t < 8; ++t) vts[(cc * 8 + t) * 72 + r] = pv[t];
        }
        __syncthreads();

        // scores: 16 q x 64 k
        f32x4 s[4] = {};
        #pragma unroll
        for (int ks = 0; ks < 5; ++ks) {
            #pragma unroll
            for (int n = 0; n < 4; ++n) {
                short8 bfr = *(const short8*)&kls[(n * 16 + l16) * 168 + ks * 32 + lhi * 8];
                s[n] = __builtin_amdgcn_mfma_f32_16x16x32_bf16(qf[ks], bfr, s[n], 0, 0, 0);
            }
        }
        #pragma unroll
        for (int n = 0; n < 4; ++n) {
            float mb = maskbias[b * SN_ + kt * 64 + n * 16 + l16];
            #pragma unroll
            for (int r = 0; r < 4; ++r) s[n][r] = s[n][r] * inv + mb;
        }
        // online softmax (row = lhi*4 + r)
        float tmax[4];
        #pragma unroll
        for (int r = 0; r < 4; ++r)
            tmax[r] = fmaxf(fmaxf(s[0][r], s[1][r]), fmaxf(s[2][r], s[3][r]));
        #pragma unroll
        for (int msk = 1; msk <= 8; msk <<= 1)
            #pragma unroll
            for (int r = 0; r < 4; ++r) tmax[r] = fmaxf(tmax[r], __shfl_xor(tmax[r], msk));
        float scale[4];
        #pragma unroll
        for (int r = 0; r < 4; ++r) {
            float mn = fmaxf(mrun[r], tmax[r]);
            scale[r] = __expf(mrun[r] - mn);
            mrun[r] = mn;
        }
        float rs[4] = {0.f, 0.f, 0.f, 0.f};
        u16 pb[4][4];
        #pragma unroll
        for (int n = 0; n < 4; ++n)
            #pragma unroll
            for (int r = 0; r < 4; ++r) {
                float p = __expf(s[n][r] - mrun[r]);
                rs[r] += p;
                pb[n][r] = f2bf(p);
            }
        #pragma unroll
        for (int msk = 1; msk <= 8; msk <<= 1)
            #pragma unroll
            for (int r = 0; r < 4; ++r) rs[r] += __shfl_xor(rs[r], msk);
        #pragma unroll
        for (int r = 0; r < 4; ++r) lrun[r] = lrun[r] * scale[r] + rs[r];
        #pragma unroll
        for (int f = 0; f < 9; ++f)
            #pragma unroll
            for (int r = 0; r < 4; ++r) o[f][r] *= scale[r];
        // P -> LDS (per-wave)
        #pragma unroll
        for (int n = 0; n < 4; ++n)
            #pragma unroll
            for (int r = 0; r < 4; ++r)
                pls[wave][(lhi * 4 + r) * 72 + n * 16 + l16] = pb[n][r];
        // PV
        #pragma unroll
        for (int ks2 = 0; ks2 < 2; ++ks2) {
            short8 pa = *(const short8*)&pls[wave][l16 * 72 + ks2 * 32 + lhi * 8];
            #pragma unroll
            for (int f = 0; f < 9; ++f) {
                short8 bv = *(const short8*)&vts[(l16 + f * 16) * 72 + ks2 * 32 + lhi * 8];
                o[f] = __builtin_amdgcn_mfma_f32_16x16x32_bf16(pa, bv, o[f], 0, 0, 0);
            }
        }
    }
    // write O (bf16) into the Q slot
    #pragma unroll
    for (int f = 0; f < 9; ++f) {
        int d = f * 16 + l16;
        if (d < HD_) {
            #pragma unroll
            for (int r = 0; r < 4; ++r) {
                size_t row = (size_t)b * SN_ + q0 + lhi * 4 + r;
                qkv[row * DM3_ + h * HD_ + d] = f2bf(o[f][r] / lrun[r]);
            }
        }
    }
}

// ---------------- residual + LayerNorm (bf16 in/out, fp32 math) ----------------
__global__ __launch_bounds__(256)
void add_ln(u16* __restrict__ x, const u16* __restrict__ o,
            const float* __restrict__ w, const float* __restrict__ bb) {
    const int row = blockIdx.x;
    const int tid = threadIdx.x;
    u16* xr = x + (size_t)row * DM_;
    const u16* orr = o + (size_t)row * DM_;
    float v0[4], v1[4];
    float s = 0.f, s2 = 0.f;
    {
        ushort4 a = ((const ushort4*)xr)[tid];
        ushort4 c = ((const ushort4*)orr)[tid];
        v0[0] = bf2f(a.x) + bf2f(c.x); v0[1] = bf2f(a.y) + bf2f(c.y);
        v0[2] = bf2f(a.z) + bf2f(c.z); v0[3] = bf2f(a.w) + bf2f(c.w);
        #pragma unroll
        for (int t = 0; t < 4; ++t) { s += v0[t]; s2 += v0[t] * v0[t]; }
    }
    const bool has2 = tid < 16;
    if (has2) {
        ushort4 a = ((const ushort4*)xr)[256 + tid];
        ushort4 c = ((const ushort4*)orr)[256 + tid];
        v1[0] = bf2f(a.x) + bf2f(c.x); v1[1] = bf2f(a.y) + bf2f(c.y);
        v1[2] = bf2f(a.z) + bf2f(c.z); v1[3] = bf2f(a.w) + bf2f(c.w);
        #pragma unroll
        for (int t = 0; t < 4; ++t) { s += v1[t]; s2 += v1[t] * v1[t]; }
    }
    #pragma unroll
    for (int m = 32; m >= 1; m >>= 1) { s += __shfl_xor(s, m); s2 += __shfl_xor(s2, m); }
    __shared__ float red[8];
    const int wave = tid >> 6, lane = tid & 63;
    if (lane == 0) { red[wave] = s; red[4 + wave] = s2; }
    __syncthreads();
    s = red[0] + red[1] + red[2] + red[3];
    s2 = red[4] + red[5] + red[6] + red[7];
    const float mean = s * (1.f / DM_);
    float var = s2 * (1.f / DM_) - mean * mean;
    const float rstd = rsqrtf(fmaxf(var, 0.f) + 1e-5f);
    {
        float4 wv = ((const float4*)w)[tid], bv = ((const float4*)bb)[tid];
        ushort4 y;
        y.x = f2bf((v0[0] - mean) * rstd * wv.x + bv.x);
        y.y = f2bf((v0[1] - mean) * rstd * wv.y + bv.y);
        y.z = f2bf((v0[2] - mean) * rstd * wv.z + bv.z);
        y.w = f2bf((v0[3] - mean) * rstd * wv.w + bv.w);
        ((ushort4*)xr)[tid] = y;
    }
    if (has2) {
        float4 wv = ((const float4*)w)[256 + tid], bv = ((const float4*)bb)[256 + tid];
        ushort4 y;
        y.x = f2bf((v1[0] - mean) * rstd * wv.x + bv.x);
        y.y = f2bf((v1[1] - mean) * rstd * wv.y + bv.y);
        y.z = f2bf((v1[2] - mean) * rstd * wv.z + bv.z);
        y.w = f2bf((v1[3] - mean) * rstd * wv.w + bv.w);
        ((ushort4*)xr)[256 + tid] = y;
    }
}

// ---------------- extract outputs (bf16 x -> fp32 out) ----------------
__global__ void extract_out(const u16* __restrict__ x, float* __restrict__ out) {
    int idx = blockIdx.x * 256 + threadIdx.x;
    const int total = B_ * 25 * D_;
    if (idx >= total) return;
    int b = idx / (25 * D_);
    int rem = idx - b * 25 * D_;
    int s = rem / D_;
    int c = rem - s * D_;
    float v = bf2f(x[((size_t)b * SN_ + s) * DM_ + c]);
    size_t dst;
    if (s == 0)       dst = (size_t)b * D_ + c;
    else if (s < 13)  dst = (size_t)B_ * D_ + ((size_t)b * 12 + (s - 1)) * D_ + c;
    else              dst = (size_t)B_ * D_ * 13 + ((size_t)b * 12 + (s - 13)) * D_ + c;
    out[dst] = v;
}

extern "C" void kernel_launch(void* const* d_in, const int* in_sizes, int n_in,
                              void* d_out, int out_size, void* d_ws, size_t ws_size,
                              hipStream_t stream) {
    const float* q_emb = (const float*)d_in[0];
    const float* sa_emb = (const float*)d_in[1];
    const float* si_emb = (const float*)d_in[2];
    const int* asz = (const int*)d_in[3];
    const int* isz = (const int*)d_in[4];
    const float* refset = (const float*)d_in[5];
    const float* Wqkv = (const float*)d_in[6];
    const float* bqkv = (const float*)d_in[7];
    const float* Wo = (const float*)d_in[8];
    const float* bo = (const float*)d_in[9];
    const float* ln1w = (const float*)d_in[10];
    const float* ln1b = (const float*)d_in[11];
    const float* W1 = (const float*)d_in[12];
    const float* b1 = (const float*)d_in[13];
    const float* W2 = (const float*)d_in[14];
    const float* b2 = (const float*)d_in[15];
    const float* ln2w = (const float*)d_in[16];
    const float* ln2b = (const float*)d_in[17];

    char* ws = (char*)d_ws;
    auto alloc = [&](size_t bytes) { char* p = ws; ws += (bytes + 255) & ~(size_t)255; return p; };
    const size_t NW_QKV = (size_t)2 * DM3_ * DM_;
    const size_t NW_O = (size_t)2 * DM_ * DM_;
    const size_t NW_1 = (size_t)2 * DFF_ * DM_;
    const size_t NROW = (size_t)B_ * SN_;

    u16* wqkv_b = (u16*)alloc(NW_QKV * 2);   // 14.2 MB
    u16* wo_b   = (u16*)alloc(NW_O * 2);     //  4.7 MB
    u16* w1_b   = (u16*)alloc(NW_1 * 2);     //  8.9 MB
    u16* w2_b   = (u16*)alloc(NW_1 * 2);     //  8.9 MB
    float* mb   = (float*)alloc(NROW * 4);   //  0.13 MB
    u16* xb     = (u16*)alloc(NROW * DM_ * 2);   // 71.3 MB
    u16* qkvb   = (u16*)alloc(NROW * DM3_ * 2);  // 213.9 MB (aliased by FFN hidden)
    u16* ob     = (u16*)alloc(NROW * DM_ * 2);   // 71.3 MB
    u16* bh     = qkvb;  // FFN hidden aliases qkv region (dead after Wo GEMM)
    // total ~393 MB

    // weights -> bf16
    cvt_bf16<<<(int)((NW_QKV + 255) / 256), 256, 0, stream>>>(Wqkv, wqkv_b, (int)NW_QKV);
    cvt_bf16<<<(int)((NW_O + 255) / 256), 256, 0, stream>>>(Wo, wo_b, (int)NW_O);
    cvt_bf16<<<(int)((NW_1 + 255) / 256), 256, 0, stream>>>(W1, w1_b, (int)NW_1);
    cvt_bf16<<<(int)((NW_1 + 255) / 256), 256, 0, stream>>>(W2, w2_b, (int)NW_1);

    // S + mask
    {
        int total = B_ * SN_ * (DM_ / 4);
        build_s<<<(total + 255) / 256, 256, 0, stream>>>(q_emb, sa_emb, si_emb, refset, xb);
        build_mask<<<(B_ * SN_ + 255) / 256, 256, 0, stream>>>(asz, isz, mb);
    }

    const int MB256 = (int)(NROW / 256);  // 128 row-blocks
    const int NBX_QKV = (DM3_ + 255) / 256;  // 13
    const int NBX_DM  = (DM_ + 255) / 256;   // 5
    const int NBX_FF  = DFF_ / 256;          // 8
    for (int l = 0; l < 2; ++l) {
        // QKV: [32768,1088] x [3264,1088]^T -> qkv bf16
        gemm256<0><<<dim3(MB256 * NBX_QKV), 512, 0, stream>>>(
            xb, DM_, wqkv_b + (size_t)l * DM3_ * DM_, bqkv + (size_t)l * DM3_, qkvb, DM3_, DM_, NBX_QKV);
        // attention (O written into Q slot of qkvb)
        attn_kernel<<<dim3(8, H_, B_), 256, 0, stream>>>(qkvb, mb);
        // Wo: A = O (Q slot of qkvb, lda=3264) -> ob
        gemm256<0><<<dim3(MB256 * NBX_DM), 512, 0, stream>>>(
            qkvb, DM3_, wo_b + (size_t)l * DM_ * DM_, bo + (size_t)l * DM_, ob, DM_, DM_, NBX_DM);
        add_ln<<<(int)NROW, 256, 0, stream>>>(xb, ob, ln1w + (size_t)l * DM_, ln1b + (size_t)l * DM_);
        // FFN
        gemm256<1><<<dim3(MB256 * NBX_FF), 512, 0, stream>>>(
            xb, DM_, w1_b + (size_t)l * DFF_ * DM_, b1 + (size_t)l * DFF_, bh, DFF_, DM_, NBX_FF);
        gemm256<0><<<dim3(MB256 * NBX_DM), 512, 0, stream>>>(
            bh, DFF_, w2_b + (size_t)l * DM_ * DFF_, b2 + (size_t)l * DM_, ob, DM_, DFF_, NBX_DM);
        add_ln<<<(int)NROW, 256, 0, stream>>>(xb, ob, ln2w + (size_t)l * DM_, ln2b + (size_t)l * DM_);
    }

    extract_out<<<(B_ * 25 * D_ + 255) / 256, 256, 0, stream>>>(xb, (float*)d_out);
}